// Round 1
// baseline (96.531 us; speedup 1.0000x reference)
//
#include <hip/hip_runtime.h>

// ---------------- compile-time problem constants ----------------
constexpr int LW    = 50;            // L
constexpr int T     = 16384;
constexpr int B     = 2;
constexpr int NK    = 11;            // ks = -5..5
constexpr int TOUT  = T - 2 * LW;    // 16284
constexpr int HALO  = 26;            // max |shift|: |m|<=25, |n|<=25, |m+n|<=26, |k|<=5
constexpr int TTILE = 128;
constexpr int SPLITS = 4;
constexpr int PACK_STRIDE = 48;      // floats per (m,n) pair in packed coeff buffer

constexpr int count_mn() {
    int c = 0;
    for (int m = -25; m <= 25; ++m)
        for (int n = -25; n <= 25; ++n) {
            int p = m * n; if (p < 0) p = -p;
            if (p <= 25) ++c;
        }
    return c;
}
constexpr int NMN = count_mn();      // 449

struct MNTab { signed char m[NMN]; signed char n[NMN]; };
constexpr MNTab make_mn() {
    MNTab t{};
    int idx = 0;
    for (int m = -25; m <= 25; ++m)
        for (int n = -25; n <= 25; ++n) {
            int p = m * n; if (p < 0) p = -p;
            if (p <= 25) { t.m[idx] = (signed char)m; t.n[idx] = (signed char)n; ++idx; }
        }
    return t;
}
constexpr MNTab MN_CONST = make_mn();
__constant__ MNTab MN = MN_CONST;

// ---------------- per-batch runtime params ----------------
__device__ inline void batch_params(const float* __restrict__ ti, int b,
                                    int& ind, float& p3, float& p5) {
    float r = ti[b * 4 + 2] * (1.0f / 2.0e9f);
    int x = (int)r;                               // trunc toward zero, matches astype(int32)
    ind = (x == 20) ? 0 : (x == 40) ? 1 : (x == 80) ? 2 : (x == 160) ? 3 : 0;
    // P = 10^(ti0/10)
    float P = exp2f(ti[b * 4 + 0] * 0.1f * 3.3219280948873623f);
    float sp = sqrtf(P);
    p3 = P * sp;          // sqrt(P)^3
    p5 = P * P * sp;      // sqrt(P)^5
}

// ---------------- coefficient pack kernel ----------------
// layout per pair j (48 floats, 16B aligned):
// [0]=cpr [1]=cpi [2+k]=c1r[k] [13+k]=c1i[k] [24+k]=c2r[k] [35+k]=c2i[k] [46..47]=pad
__global__ void pack_coeffs(const float* __restrict__ ti,
                            const float* __restrict__ pCr, const float* __restrict__ pCi,
                            const float* __restrict__ C1r, const float* __restrict__ C1i,
                            const float* __restrict__ C2r, const float* __restrict__ C2i,
                            float* __restrict__ packed) {
    int j = blockIdx.x * blockDim.x + threadIdx.x;
    int b = blockIdx.y;
    if (j >= NMN) return;
    int ind; float p3, p5;
    batch_params(ti, b, ind, p3, p5);
    float* d = packed + ((size_t)b * NMN + j) * PACK_STRIDE;
    d[0] = pCr[(size_t)ind * NMN + j];
    d[1] = pCi[(size_t)ind * NMN + j];
    const float* a1r = C1r + ((size_t)ind * NMN + j) * NK;
    const float* a1i = C1i + ((size_t)ind * NMN + j) * NK;
    const float* a2r = C2r + ((size_t)ind * NMN + j) * NK;
    const float* a2i = C2i + ((size_t)ind * NMN + j) * NK;
#pragma unroll
    for (int k = 0; k < NK; ++k) {
        d[2 + k]  = a1r[k];
        d[13 + k] = a1i[k];
        d[24 + k] = a2r[k];
        d[35 + k] = a2i[k];
    }
    d[46] = 0.f; d[47] = 0.f;
}

// ---------------- main kernel ----------------
// grid: (ntiles, B, nsplit). Each block: one 128-wide t tile, one j-range split.
// dst layout: ((split*B + b)*TOUT + t')*2  — with nsplit==1 this IS the out layout.
template <bool PACKED>
__global__ __launch_bounds__(TTILE) void sopbc_main(
    const float* __restrict__ Er, const float* __restrict__ Ei,
    const float* __restrict__ ti,
    const float* __restrict__ pCr, const float* __restrict__ pCi,
    const float* __restrict__ C1r, const float* __restrict__ C1i,
    const float* __restrict__ C2r, const float* __restrict__ C2i,
    const float* __restrict__ packed,
    float* __restrict__ dst)
{
    const int b = blockIdx.y;
    const int split = blockIdx.z;
    const int nsplit = gridDim.z;
    const int t0 = LW + blockIdx.x * TTILE;
    const int tid = threadIdx.x;

    int ind; float p3, p5;
    batch_params(ti, b, ind, p3, p5);

    __shared__ float2 Es[TTILE + 2 * HALO + 1];
#pragma unroll
    for (int i = tid; i < TTILE + 2 * HALO + 1; i += TTILE) {
        int tt = t0 - HALO + i;
        float2 v = {0.f, 0.f};
        if (tt >= 0 && tt < T) {
            v.x = Er[(size_t)b * T + tt];
            v.y = Ei[(size_t)b * T + tt];
        }
        Es[i] = v;
    }
    __syncthreads();

    const int t = t0 + tid;
    const int base = tid + HALO;

    const int j0 = (NMN * split) / nsplit;
    const int j1 = (NMN * (split + 1)) / nsplit;

    float s1r = 0.f, s1i = 0.f;
    float g1r[NK] = {}, g1i[NK] = {}, g2r[NK] = {}, g2i[NK] = {};

    const float* cpr = pCr + (size_t)ind * NMN;
    const float* cpi = pCi + (size_t)ind * NMN;
    const float* a1r = C1r + (size_t)ind * NMN * NK;
    const float* a1i = C1i + (size_t)ind * NMN * NK;
    const float* a2r = C2r + (size_t)ind * NMN * NK;
    const float* a2i = C2i + (size_t)ind * NMN * NK;

    for (int j = j0; j < j1; ++j) {
        const int m = MN.m[j];
        const int n = MN.n[j];
        const float2 en  = Es[base - n];
        const float2 emn = Es[base - m - n];
        const float2 em  = Es[base - m];
        // A = E[t-n] * conj(E[t-m-n]) * E[t-m]
        const float ar1 = en.x * emn.x + en.y * emn.y;
        const float ai1 = en.y * emn.x - en.x * emn.y;
        const float Ar = ar1 * em.x - ai1 * em.y;
        const float Ai = ar1 * em.y + ai1 * em.x;

        float c[PACK_STRIDE];
        if constexpr (PACKED) {
            const float4* q = (const float4*)(packed + ((size_t)b * NMN + j) * PACK_STRIDE);
#pragma unroll
            for (int i4 = 0; i4 < 12; ++i4) {
                float4 v = q[i4];
                c[4 * i4 + 0] = v.x; c[4 * i4 + 1] = v.y;
                c[4 * i4 + 2] = v.z; c[4 * i4 + 3] = v.w;
            }
        } else {
            c[0] = cpr[j]; c[1] = cpi[j];
#pragma unroll
            for (int k = 0; k < NK; ++k) {
                c[2 + k]  = a1r[j * NK + k];
                c[13 + k] = a1i[j * NK + k];
                c[24 + k] = a2r[j * NK + k];
                c[35 + k] = a2i[j * NK + k];
            }
        }

        // sum1 += A * Cp
        s1r += Ar * c[0] - Ai * c[1];
        s1i += Ar * c[1] + Ai * c[0];
#pragma unroll
        for (int k = 0; k < NK; ++k) {
            const float x1 = c[2 + k],  y1 = c[13 + k];
            g1r[k] += Ar * x1 - Ai * y1;      // A * C1
            g1i[k] += Ar * y1 + Ai * x1;
            const float x2 = c[24 + k], y2 = c[35 + k];
            g2r[k] += Ar * x2 + Ai * y2;      // conj(A) * C2
            g2i[k] += Ar * y2 - Ai * x2;
        }
    }

    if (t < T - LW) {
        float accr = 0.f, acci = 0.f;
#pragma unroll
        for (int k = 0; k < NK; ++k) {
            const int ks = k - NK / 2;   // -5..5
            const float2 ek = Es[base - ks];
            const float Iv = ek.x * ek.x + ek.y * ek.y;   // |E|^2 (real)
            const float Qr = ek.x * ek.x - ek.y * ek.y;   // E^2
            const float Qi = 2.f * ek.x * ek.y;
            accr += Iv * g1r[k] + Qr * g2r[k] - Qi * g2i[k];
            acci += Iv * g1i[k] + Qr * g2i[k] + Qi * g2r[k];
        }
        float outr = p3 * s1r + p5 * accr;
        float outi = p3 * s1i + p5 * acci;
        if (split == 0) {               // base E term exactly once
            const float2 e = Es[base];
            outr += e.x; outi += e.y;
        }
        const size_t o = (((size_t)split * B + b) * TOUT + (size_t)(t - LW)) * 2;
        dst[o]     = outr;
        dst[o + 1] = outi;
    }
}

// ---------------- combine partials ----------------
__global__ void combine_kernel(const float* __restrict__ part, float* __restrict__ out,
                               int n, int nsplit) {
    int i = blockIdx.x * blockDim.x + threadIdx.x;
    if (i < n) {
        float s = 0.f;
        for (int sp = 0; sp < nsplit; ++sp) s += part[(size_t)sp * n + i];
        out[i] = s;
    }
}

// ---------------- launch ----------------
extern "C" void kernel_launch(void* const* d_in, const int* in_sizes, int n_in,
                              void* d_out, int out_size, void* d_ws, size_t ws_size,
                              hipStream_t stream) {
    const float* Er  = (const float*)d_in[0];
    const float* Ei  = (const float*)d_in[1];
    const float* ti  = (const float*)d_in[2];
    const float* pCr = (const float*)d_in[3];
    const float* pCi = (const float*)d_in[4];
    const float* C1r = (const float*)d_in[5];
    const float* C1i = (const float*)d_in[6];
    const float* C2r = (const float*)d_in[7];
    const float* C2i = (const float*)d_in[8];
    float* out = (float*)d_out;

    const int ntiles = (TOUT + TTILE - 1) / TTILE;
    const size_t packBytes = (size_t)B * NMN * PACK_STRIDE * sizeof(float);
    const size_t partBytes = (size_t)SPLITS * B * TOUT * 2 * sizeof(float);

    if (ws_size >= packBytes + partBytes) {
        float* packed = (float*)d_ws;
        float* part   = (float*)((char*)d_ws + packBytes);

        hipLaunchKernelGGL(pack_coeffs, dim3((NMN + 127) / 128, B), dim3(128), 0, stream,
                           ti, pCr, pCi, C1r, C1i, C2r, C2i, packed);
        hipLaunchKernelGGL((sopbc_main<true>), dim3(ntiles, B, SPLITS), dim3(TTILE), 0, stream,
                           Er, Ei, ti, pCr, pCi, C1r, C1i, C2r, C2i, packed, part);
        const int n = B * TOUT * 2;
        hipLaunchKernelGGL(combine_kernel, dim3((n + 255) / 256), dim3(256), 0, stream,
                           part, out, n, SPLITS);
    } else {
        // fallback: no scratch — single pass, direct coefficient loads
        hipLaunchKernelGGL((sopbc_main<false>), dim3(ntiles, B, 1), dim3(TTILE), 0, stream,
                           Er, Ei, ti, pCr, pCi, C1r, C1i, C2r, C2i, nullptr, out);
    }
}

// Round 2
// 61.614 us; speedup vs baseline: 1.5667x; 1.5667x over previous
//
#include <hip/hip_runtime.h>

// ---------------- compile-time problem constants ----------------
constexpr int LW    = 50;            // L
constexpr int T     = 16384;
constexpr int B     = 2;
constexpr int NK    = 11;            // ks = -5..5
constexpr int TOUT  = T - 2 * LW;    // 16284
constexpr int HALO  = 26;            // max |shift|: |m|<=25, |n|<=25, |m+n|<=26, |k|<=5
constexpr int TTILE = 256;
constexpr int SPLITS = 16;
constexpr int PACK_STRIDE = 48;      // floats per (m,n) pair in packed coeff buffer

constexpr int count_mn() {
    int c = 0;
    for (int m = -25; m <= 25; ++m)
        for (int n = -25; n <= 25; ++n) {
            int p = m * n; if (p < 0) p = -p;
            if (p <= 25) ++c;
        }
    return c;
}
constexpr int NMN = count_mn();      // 449

struct MNTab { signed char m[NMN]; signed char n[NMN]; };
constexpr MNTab make_mn() {
    MNTab t{};
    int idx = 0;
    for (int m = -25; m <= 25; ++m)
        for (int n = -25; n <= 25; ++n) {
            int p = m * n; if (p < 0) p = -p;
            if (p <= 25) { t.m[idx] = (signed char)m; t.n[idx] = (signed char)n; ++idx; }
        }
    return t;
}
constexpr MNTab MN_CONST = make_mn();
__constant__ MNTab MN = MN_CONST;

// ---------------- per-batch runtime params ----------------
__device__ inline void batch_params(const float* __restrict__ ti, int b,
                                    int& ind, float& p3, float& p5) {
    float r = ti[b * 4 + 2] * (1.0f / 2.0e9f);
    int x = (int)r;                               // trunc, matches astype(int32)
    ind = (x == 20) ? 0 : (x == 40) ? 1 : (x == 80) ? 2 : (x == 160) ? 3 : 0;
    float P = exp2f(ti[b * 4 + 0] * 0.1f * 3.3219280948873623f);   // 10^(ti0/10)
    float sp = sqrtf(P);
    p3 = P * sp;          // sqrt(P)^3
    p5 = P * P * sp;      // sqrt(P)^5
}

// ---------------- coefficient pack kernel ----------------
// layout per pair j (48 floats, 16B aligned):
// [0]=cpr [1]=cpi [2..3]=pad, then per k (k=0..10): [4+4k]=x1 [5+4k]=y1 [6+4k]=x2 [7+4k]=y2
__global__ void pack_coeffs(const float* __restrict__ ti,
                            const float* __restrict__ pCr, const float* __restrict__ pCi,
                            const float* __restrict__ C1r, const float* __restrict__ C1i,
                            const float* __restrict__ C2r, const float* __restrict__ C2i,
                            float* __restrict__ packed) {
    int j = blockIdx.x * blockDim.x + threadIdx.x;
    int b = blockIdx.y;
    if (j >= NMN) return;
    int ind; float p3, p5;
    batch_params(ti, b, ind, p3, p5);
    float* d = packed + ((size_t)b * NMN + j) * PACK_STRIDE;
    d[0] = pCr[(size_t)ind * NMN + j];
    d[1] = pCi[(size_t)ind * NMN + j];
    d[2] = 0.f; d[3] = 0.f;
    const float* a1r = C1r + ((size_t)ind * NMN + j) * NK;
    const float* a1i = C1i + ((size_t)ind * NMN + j) * NK;
    const float* a2r = C2r + ((size_t)ind * NMN + j) * NK;
    const float* a2i = C2i + ((size_t)ind * NMN + j) * NK;
#pragma unroll
    for (int k = 0; k < NK; ++k) {
        d[4 + 4 * k] = a1r[k];
        d[5 + 4 * k] = a1i[k];
        d[6 + 4 * k] = a2r[k];
        d[7 + 4 * k] = a2i[k];
    }
}

// ---------------- main kernel ----------------
// Sum-order-swapped formulation: per thread precompute Iv/Qr/Qi[k] once, then
// per j contract coefficients against them:
//   D1_j = sum_k I_k*C1_jk ; D2_j = sum_k Q_k*C2_jk ; acc += A_j*D1_j + conj(A_j)*D2_j
// grid: (ntiles, B, nsplit).
// dst layout: ((split*B + b)*TOUT + t')*2
template <bool PACKED>
__global__ __launch_bounds__(TTILE) void sopbc_main(
    const float* __restrict__ Er, const float* __restrict__ Ei,
    const float* __restrict__ ti,
    const float* __restrict__ pCr, const float* __restrict__ pCi,
    const float* __restrict__ C1r, const float* __restrict__ C1i,
    const float* __restrict__ C2r, const float* __restrict__ C2i,
    const float* __restrict__ packed,
    float* __restrict__ dst)
{
    const int b = blockIdx.y;
    const int split = blockIdx.z;
    const int nsplit = gridDim.z;
    const int t0 = LW + blockIdx.x * TTILE;
    const int tid = threadIdx.x;

    int ind; float p3, p5;
    batch_params(ti, b, ind, p3, p5);

    __shared__ float2 Es[TTILE + 2 * HALO + 1];
    for (int i = tid; i < TTILE + 2 * HALO + 1; i += TTILE) {
        int tt = t0 - HALO + i;
        float2 v = {0.f, 0.f};
        if (tt >= 0 && tt < T) {
            v.x = Er[(size_t)b * T + tt];
            v.y = Ei[(size_t)b * T + tt];
        }
        Es[i] = v;
    }
    __syncthreads();

    const int t = t0 + tid;
    const int base = tid + HALO;

    // per-thread I/Q windows (k = -5..5), fully unrolled -> registers
    float Iv[NK], Qr[NK], Qi[NK];
#pragma unroll
    for (int k = 0; k < NK; ++k) {
        const int ks = k - NK / 2;
        const float2 ek = Es[base - ks];
        Iv[k] = ek.x * ek.x + ek.y * ek.y;
        Qr[k] = ek.x * ek.x - ek.y * ek.y;
        Qi[k] = 2.f * ek.x * ek.y;
    }

    const int j0 = (NMN * split) / nsplit;
    const int j1 = (NMN * (split + 1)) / nsplit;

    float s1r = 0.f, s1i = 0.f;       // sum_j A_j * Cp_j
    float accr = 0.f, acci = 0.f;     // sum_j A*D1 + conj(A)*D2

    const float* cpr = pCr + (size_t)ind * NMN;
    const float* cpi = pCi + (size_t)ind * NMN;
    const float* a1r = C1r + (size_t)ind * NMN * NK;
    const float* a1i = C1i + (size_t)ind * NMN * NK;
    const float* a2r = C2r + (size_t)ind * NMN * NK;
    const float* a2i = C2i + (size_t)ind * NMN * NK;

    for (int j = j0; j < j1; ++j) {
        const int m = MN.m[j];
        const int n = MN.n[j];
        const float2 en  = Es[base - n];
        const float2 emn = Es[base - m - n];
        const float2 em  = Es[base - m];
        // A = E[t-n] * conj(E[t-m-n]) * E[t-m]
        const float ar1 = en.x * emn.x + en.y * emn.y;
        const float ai1 = en.y * emn.x - en.x * emn.y;
        const float Ar = ar1 * em.x - ai1 * em.y;
        const float Ai = ar1 * em.y + ai1 * em.x;

        float c0, c1;
        float P1 = 0.f, P2 = 0.f, P3 = 0.f, P4 = 0.f, P5 = 0.f, P6 = 0.f;
        if constexpr (PACKED) {
            const float4* q = (const float4*)(packed + ((size_t)b * NMN + j) * PACK_STRIDE);
            float4 h = q[0];
            c0 = h.x; c1 = h.y;
#pragma unroll
            for (int k = 0; k < NK; ++k) {
                float4 v = q[1 + k];              // x1 y1 x2 y2
                P1 += Iv[k] * v.x;
                P2 += Iv[k] * v.y;
                P3 += Qr[k] * v.z;
                P4 += Qr[k] * v.w;
                P5 += Qi[k] * v.z;
                P6 += Qi[k] * v.w;
            }
        } else {
            c0 = cpr[j]; c1 = cpi[j];
#pragma unroll
            for (int k = 0; k < NK; ++k) {
                const float x1 = a1r[j * NK + k], y1 = a1i[j * NK + k];
                const float x2 = a2r[j * NK + k], y2 = a2i[j * NK + k];
                P1 += Iv[k] * x1;
                P2 += Iv[k] * y1;
                P3 += Qr[k] * x2;
                P4 += Qr[k] * y2;
                P5 += Qi[k] * x2;
                P6 += Qi[k] * y2;
            }
        }

        // s1 += A * Cp
        s1r += Ar * c0 - Ai * c1;
        s1i += Ar * c1 + Ai * c0;

        // acc += A*(P1+iP2) + conj(A)*((P3-P6) + i(P4+P5))
        const float U = P1, V = P2, W = P3 - P6, Z = P4 + P5;
        accr += Ar * (U + W) + Ai * (Z - V);
        acci += Ar * (V + Z) + Ai * (U - W);
    }

    if (t < T - LW) {
        float outr = p3 * s1r + p5 * accr;
        float outi = p3 * s1i + p5 * acci;
        if (split == 0) {               // base E term exactly once
            const float2 e = Es[base];
            outr += e.x; outi += e.y;
        }
        const size_t o = (((size_t)split * B + b) * TOUT + (size_t)(t - LW)) * 2;
        dst[o]     = outr;
        dst[o + 1] = outi;
    }
}

// ---------------- combine partials ----------------
__global__ void combine_kernel(const float* __restrict__ part, float* __restrict__ out,
                               int n, int nsplit) {
    int i = blockIdx.x * blockDim.x + threadIdx.x;
    if (i < n) {
        float s = 0.f;
        for (int sp = 0; sp < nsplit; ++sp) s += part[(size_t)sp * n + i];
        out[i] = s;
    }
}

// ---------------- launch ----------------
extern "C" void kernel_launch(void* const* d_in, const int* in_sizes, int n_in,
                              void* d_out, int out_size, void* d_ws, size_t ws_size,
                              hipStream_t stream) {
    const float* Er  = (const float*)d_in[0];
    const float* Ei  = (const float*)d_in[1];
    const float* ti  = (const float*)d_in[2];
    const float* pCr = (const float*)d_in[3];
    const float* pCi = (const float*)d_in[4];
    const float* C1r = (const float*)d_in[5];
    const float* C1i = (const float*)d_in[6];
    const float* C2r = (const float*)d_in[7];
    const float* C2i = (const float*)d_in[8];
    float* out = (float*)d_out;

    const int ntiles = (TOUT + TTILE - 1) / TTILE;
    const size_t packBytes = (size_t)B * NMN * PACK_STRIDE * sizeof(float);
    const size_t partBytes = (size_t)SPLITS * B * TOUT * 2 * sizeof(float);

    if (ws_size >= packBytes + partBytes) {
        float* packed = (float*)d_ws;
        float* part   = (float*)((char*)d_ws + packBytes);

        hipLaunchKernelGGL(pack_coeffs, dim3((NMN + 127) / 128, B), dim3(128), 0, stream,
                           ti, pCr, pCi, C1r, C1i, C2r, C2i, packed);
        hipLaunchKernelGGL((sopbc_main<true>), dim3(ntiles, B, SPLITS), dim3(TTILE), 0, stream,
                           Er, Ei, ti, pCr, pCi, C1r, C1i, C2r, C2i, packed, part);
        const int n = B * TOUT * 2;
        hipLaunchKernelGGL(combine_kernel, dim3((n + 255) / 256), dim3(256), 0, stream,
                           part, out, n, SPLITS);
    } else {
        // fallback: no scratch — single pass, direct coefficient loads
        hipLaunchKernelGGL((sopbc_main<false>), dim3(ntiles, B, 1), dim3(TTILE), 0, stream,
                           Er, Ei, ti, pCr, pCi, C1r, C1i, C2r, C2i, nullptr, out);
    }
}